// Round 4
// baseline (2048.807 us; speedup 1.0000x reference)
//
#include <hip/hip_runtime.h>
#include <hip/hip_bf16.h>

#define NN 100000
#define NE 1000000
#define DD 128
#define RR 8
#define NB 782                 // ceil(NN/128)
#define NSEG (RR*NB)           // 6256

typedef short bf16x8 __attribute__((ext_vector_type(8)));
typedef float f32x4 __attribute__((ext_vector_type(4)));

__device__ __forceinline__ unsigned short f2bf(float f) {
    union { float f; unsigned int u; } c; c.f = f;
    unsigned int u = c.u;
    u += 0x7fffu + ((u >> 16) & 1u);   // round-to-nearest-even
    return (unsigned short)(u >> 16);
}

__device__ __forceinline__ float bf2f(unsigned short s) {
    union { unsigned int u; float f; } c; c.u = ((unsigned int)s) << 16;
    return c.f;
}

// fp32 -> bf16, 4 elems/thread
__global__ __launch_bounds__(256) void cvt_x_k(const float* __restrict__ in,
                                               unsigned short* __restrict__ out,
                                               int n4) {
    int i = blockIdx.x * 256 + threadIdx.x;
    if (i >= n4) return;
    float4 v = reinterpret_cast<const float4*>(in)[i];
    ushort4 o;
    o.x = f2bf(v.x); o.y = f2bf(v.y); o.z = f2bf(v.z); o.w = f2bf(v.w);
    reinterpret_cast<ushort4*>(out)[i] = o;
}

// W [r][d][e] fp32 -> Wt [m][e][d] bf16 (m=0..7 relations, m=8 root), both layers
__global__ __launch_bounds__(256) void cvt_w_k(const float* __restrict__ W1,
                                               const float* __restrict__ r1,
                                               const float* __restrict__ W2,
                                               const float* __restrict__ r2,
                                               unsigned short* __restrict__ wt1,
                                               unsigned short* __restrict__ wt2) {
    int idx = blockIdx.x * 256 + threadIdx.x;       // 0 .. 2*9*128*128-1
    int l   = idx / (9 * DD * DD);
    int rem = idx % (9 * DD * DD);
    int m   = rem / (DD * DD);
    int ed  = rem % (DD * DD);
    int e = ed / DD, d = ed % DD;
    const float* srcm = (l == 0) ? (m < 8 ? W1 + (size_t)m * DD * DD : r1)
                                 : (m < 8 ? W2 + (size_t)m * DD * DD : r2);
    unsigned short* o = (l == 0) ? wt1 : wt2;
    o[rem] = f2bf(srcm[(size_t)d * DD + e]);        // transpose: Wt[e][d] = W[d][e]
}

// per-(r,dst) degree + per-(r,block) segment counts
__global__ __launch_bounds__(256) void hist_k(const int* __restrict__ dst,
                                              const int* __restrict__ et,
                                              unsigned int* __restrict__ deg,
                                              unsigned int* __restrict__ blkcnt) {
    int e = blockIdx.x * 256 + threadIdx.x;
    if (e >= NE) return;
    int d = dst[e], r = et[e];
    atomicAdd(&deg[(size_t)r * NN + d], 1u);
    atomicAdd(&blkcnt[r * NB + (d >> 7)], 1u);
}

// single-block exclusive scan of blkcnt -> blkoff (+ copy to fillptr)
__global__ __launch_bounds__(256) void scan_k(const unsigned int* __restrict__ blkcnt,
                                              unsigned int* __restrict__ blkoff,
                                              unsigned int* __restrict__ fillptr) {
    __shared__ unsigned int part[256];
    const int tid = threadIdx.x;
    const int PER = (NSEG + 255) / 256;             // 25
    unsigned int sum = 0;
    for (int i = 0; i < PER; ++i) {
        int idx = tid * PER + i;
        if (idx < NSEG) sum += blkcnt[idx];
    }
    part[tid] = sum;
    __syncthreads();
    for (int off = 1; off < 256; off <<= 1) {
        unsigned int v = (tid >= off) ? part[tid - off] : 0u;
        __syncthreads();
        part[tid] += v;
        __syncthreads();
    }
    unsigned int run = (tid == 0) ? 0u : part[tid - 1];
    for (int i = 0; i < PER; ++i) {
        int idx = tid * PER + i;
        if (idx < NSEG) {
            blkoff[idx] = run;
            fillptr[idx] = run;
            run += blkcnt[idx];
        }
    }
    if (tid == 0) blkoff[NSEG] = part[255];
}

// scatter packed records into (r, dst-block) segments: src | dstloc<<17 | deg<<24
__global__ __launch_bounds__(256) void fill_k(const int* __restrict__ src,
                                              const int* __restrict__ dst,
                                              const int* __restrict__ et,
                                              const unsigned int* __restrict__ deg,
                                              unsigned int* __restrict__ fillptr,
                                              unsigned int* __restrict__ sorted) {
    int e = blockIdx.x * 256 + threadIdx.x;
    if (e >= NE) return;
    int s = src[e], d = dst[e], r = et[e];
    unsigned int p = atomicAdd(&fillptr[r * NB + (d >> 7)], 1u);
    unsigned int dg = deg[(size_t)r * NN + d];
    if (dg > 255u) dg = 255u;
    sorted[p] = (unsigned int)s | ((unsigned int)(d & 127) << 17) | (dg << 24);
}

// Fused RGCN layer: per 128-dst block, for each relation r:
//   gather mean(x[src]) into XOR-swizzled LDS tile, then MFMA with W[r],
// accumulating in registers across relations + root + bias + relu.
// mode 1: store bf16 (next-layer input). mode 2: store f32 (final output).
__global__ __launch_bounds__(256) void fused_k(const unsigned short* __restrict__ xb,
                                               const unsigned short* __restrict__ wt,
                                               const float* __restrict__ bias,
                                               const unsigned int* __restrict__ sorted,
                                               const unsigned int* __restrict__ blkoff,
                                               unsigned short* __restrict__ obf,
                                               float* __restrict__ of32,
                                               int mode) {
    __shared__ float xagg[128 * 128];               // 64 KB, XOR-swizzled columns
    const int wave = threadIdx.x >> 6;
    const int lane = threadIdx.x & 63;
    const int c16  = lane & 15;
    const int grp  = lane >> 4;
    const int blk  = blockIdx.x;
    const int nodeBase = blk * 128 + wave * 32;

    f32x4 acc[8][2];
#pragma unroll
    for (int oc = 0; oc < 8; ++oc) {
        acc[oc][0] = f32x4{0.f, 0.f, 0.f, 0.f};
        acc[oc][1] = f32x4{0.f, 0.f, 0.f, 0.f};
    }

    for (int r = 0; r < RR; ++r) {
        // zero LDS tile (4096 float4 / 256 threads = 16 each)
        const float4 z4 = make_float4(0.f, 0.f, 0.f, 0.f);
#pragma unroll
        for (int i = 0; i < 16; ++i)
            reinterpret_cast<float4*>(xagg)[threadIdx.x + i * 256] = z4;
        __syncthreads();

        const int rb = (int)blkoff[r * NB + blk];
        const int re = (int)blkoff[r * NB + blk + 1];
        // gather: 4 waves interleave chunks of 8 edges; 8 loads in flight
        for (int j0 = rb + wave * 8; j0 < re; j0 += 32) {
            int n = re - j0; if (n > 8) n = 8;
            unsigned int pk[8], hv[8];
#pragma unroll
            for (int u = 0; u < 8; ++u)
                if (u < n) pk[u] = sorted[j0 + u];
#pragma unroll
            for (int u = 0; u < 8; ++u)
                if (u < n) hv[u] = *reinterpret_cast<const unsigned int*>(
                        xb + (size_t)(pk[u] & 0x1FFFFu) * DD + lane * 2);
#pragma unroll
            for (int u = 0; u < 8; ++u)
                if (u < n) {
                    float sc = __builtin_amdgcn_rcpf((float)(pk[u] >> 24));
                    int dl = (pk[u] >> 17) & 127;
                    int base = dl * 128 + ((((lane >> 1) ^ (dl & 7)) << 2) | ((lane & 1) << 1));
                    atomicAdd(&xagg[base],     bf2f((unsigned short)(hv[u] & 0xffffu)) * sc);
                    atomicAdd(&xagg[base + 1], bf2f((unsigned short)(hv[u] >> 16)) * sc);
                }
        }
        __syncthreads();

        // B fragments from LDS (f32 -> bf16)
        bf16x8 bfr[2][4];
#pragma unroll
        for (int nt = 0; nt < 2; ++nt) {
            int n = wave * 32 + nt * 16 + c16;
#pragma unroll
            for (int kk = 0; kk < 4; ++kk) {
                int c4 = kk * 8 + grp * 2;
                float4 lo = *reinterpret_cast<const float4*>(&xagg[n * 128 + (((c4    ) ^ (n & 7)) << 2)]);
                float4 hi = *reinterpret_cast<const float4*>(&xagg[n * 128 + (((c4 + 1) ^ (n & 7)) << 2)]);
                union { unsigned short s[8]; bf16x8 v; } pkv;
                pkv.s[0] = f2bf(lo.x); pkv.s[1] = f2bf(lo.y);
                pkv.s[2] = f2bf(lo.z); pkv.s[3] = f2bf(lo.w);
                pkv.s[4] = f2bf(hi.x); pkv.s[5] = f2bf(hi.y);
                pkv.s[6] = f2bf(hi.z); pkv.s[7] = f2bf(hi.w);
                bfr[nt][kk] = pkv.v;
            }
        }

        const unsigned short* wm = wt + (size_t)r * DD * DD;
#pragma unroll
        for (int oc = 0; oc < 8; ++oc) {
            bf16x8 a[4];
            const unsigned short* wrow = wm + (size_t)(oc * 16 + c16) * DD;
#pragma unroll
            for (int kk = 0; kk < 4; ++kk)
                a[kk] = *reinterpret_cast<const bf16x8*>(wrow + kk * 32 + grp * 8);
#pragma unroll
            for (int kk = 0; kk < 4; ++kk) {
                acc[oc][0] = __builtin_amdgcn_mfma_f32_16x16x32_bf16(a[kk], bfr[0][kk], acc[oc][0], 0, 0, 0);
                acc[oc][1] = __builtin_amdgcn_mfma_f32_16x16x32_bf16(a[kk], bfr[1][kk], acc[oc][1], 0, 0, 0);
            }
        }
        __syncthreads();   // protect xagg before next relation's zeroing
    }

    // root term: B-frags from global xb
    {
        bf16x8 bfr[2][4];
#pragma unroll
        for (int nt = 0; nt < 2; ++nt) {
            int node = nodeBase + nt * 16 + c16;
            if (node > NN - 1) node = NN - 1;
            const unsigned short* xrow = xb + (size_t)node * DD;
#pragma unroll
            for (int kk = 0; kk < 4; ++kk)
                bfr[nt][kk] = *reinterpret_cast<const bf16x8*>(xrow + kk * 32 + grp * 8);
        }
        const unsigned short* wm = wt + (size_t)8 * DD * DD;
#pragma unroll
        for (int oc = 0; oc < 8; ++oc) {
            bf16x8 a[4];
            const unsigned short* wrow = wm + (size_t)(oc * 16 + c16) * DD;
#pragma unroll
            for (int kk = 0; kk < 4; ++kk)
                a[kk] = *reinterpret_cast<const bf16x8*>(wrow + kk * 32 + grp * 8);
#pragma unroll
            for (int kk = 0; kk < 4; ++kk) {
                acc[oc][0] = __builtin_amdgcn_mfma_f32_16x16x32_bf16(a[kk], bfr[0][kk], acc[oc][0], 0, 0, 0);
                acc[oc][1] = __builtin_amdgcn_mfma_f32_16x16x32_bf16(a[kk], bfr[1][kk], acc[oc][1], 0, 0, 0);
            }
        }
    }

    // epilogue: + bias, relu, store
#pragma unroll
    for (int oc = 0; oc < 8; ++oc) {
        const float4 bv = *reinterpret_cast<const float4*>(bias + oc * 16 + grp * 4);
#pragma unroll
        for (int nt = 0; nt < 2; ++nt) {
            int node = nodeBase + nt * 16 + c16;
            if (node >= NN) continue;
            float o0 = fmaxf(acc[oc][nt][0] + bv.x, 0.f);
            float o1 = fmaxf(acc[oc][nt][1] + bv.y, 0.f);
            float o2 = fmaxf(acc[oc][nt][2] + bv.z, 0.f);
            float o3 = fmaxf(acc[oc][nt][3] + bv.w, 0.f);
            if (mode == 1) {
                union { unsigned short s[4]; uint2 v; } pko;
                pko.s[0] = f2bf(o0); pko.s[1] = f2bf(o1);
                pko.s[2] = f2bf(o2); pko.s[3] = f2bf(o3);
                *reinterpret_cast<uint2*>(obf + (size_t)node * DD + oc * 16 + grp * 4) = pko.v;
            } else {
                *reinterpret_cast<float4*>(of32 + (size_t)node * DD + oc * 16 + grp * 4)
                    = make_float4(o0, o1, o2, o3);
            }
        }
    }
}

extern "C" void kernel_launch(void* const* d_in, const int* in_sizes, int n_in,
                              void* d_out, int out_size, void* d_ws, size_t ws_size,
                              hipStream_t stream) {
    const float* x  = (const float*)d_in[0];
    const int*   ei = (const int*)d_in[1];
    const int*   et = (const int*)d_in[2];
    const float* W1 = (const float*)d_in[3];
    const float* r1 = (const float*)d_in[4];
    const float* b1 = (const float*)d_in[5];
    const float* W2 = (const float*)d_in[6];
    const float* r2 = (const float*)d_in[7];
    const float* b2 = (const float*)d_in[8];
    float* out = (float*)d_out;

    // workspace (~59 MB total)
    char* ws = (char*)d_ws;
    unsigned int*   deg     = (unsigned int*)ws;                 // RR*NN u32 = 3.2 MB
    unsigned int*   blkcnt  = deg + (size_t)RR * NN;             // NSEG
    unsigned int*   blkoff  = blkcnt + NSEG;                     // NSEG+1
    unsigned int*   fillptr = blkoff + NSEG + 1;                 // NSEG
    unsigned int*   sorted  = fillptr + NSEG;                    // NE u32 = 4 MB
    unsigned short* wt1     = (unsigned short*)(sorted + NE);    // 294,912 B
    unsigned short* wt2     = wt1 + 9 * DD * DD;                 // 294,912 B
    unsigned short* xbuf    = wt2 + 9 * DD * DD;                 // 25.6 MB
    unsigned short* xbuf2   = xbuf + (size_t)NN * DD;            // 25.6 MB
    size_t need = (size_t)((char*)(xbuf2 + (size_t)NN * DD) - ws);
    if (ws_size < need) return;                                  // loud failure

    const int* srcv = ei;
    const int* dstv = ei + NE;

    hipMemsetAsync(deg, 0, ((size_t)RR * NN + NSEG) * 4, stream);
    cvt_x_k<<<(NN * DD / 4 + 255) / 256, 256, 0, stream>>>(x, xbuf, NN * DD / 4);
    cvt_w_k<<<(2 * 9 * DD * DD) / 256, 256, 0, stream>>>(W1, r1, W2, r2, wt1, wt2);
    hist_k<<<(NE + 255) / 256, 256, 0, stream>>>(dstv, et, deg, blkcnt);
    scan_k<<<1, 256, 0, stream>>>(blkcnt, blkoff, fillptr);
    fill_k<<<(NE + 255) / 256, 256, 0, stream>>>(srcv, dstv, et, deg, fillptr, sorted);

    fused_k<<<NB, 256, 0, stream>>>(xbuf,  wt1, b1, sorted, blkoff, xbuf2, (float*)nullptr, 1);
    fused_k<<<NB, 256, 0, stream>>>(xbuf2, wt2, b2, sorted, blkoff, (unsigned short*)nullptr, out, 2);
}

// Round 5
// 809.361 us; speedup vs baseline: 2.5314x; 2.5314x over previous
//
#include <hip/hip_runtime.h>
#include <hip/hip_bf16.h>

#define NN 100000
#define NE 1000000
#define DD 128
#define RR 8
#define KCAT 1152              // 9*128 (8 relations + root)
#define NBLK 6250              // NN/16 exactly

typedef short bf16x8 __attribute__((ext_vector_type(8)));
typedef float f32x4 __attribute__((ext_vector_type(4)));

__device__ __forceinline__ unsigned short f2bf(float f) {
    union { float f; unsigned int u; } c; c.f = f;
    unsigned int u = c.u;
    u += 0x7fffu + ((u >> 16) & 1u);   // round-to-nearest-even
    return (unsigned short)(u >> 16);
}

__device__ __forceinline__ float bf2f(unsigned short s) {
    union { unsigned int u; float f; } c; c.u = ((unsigned int)s) << 16;
    return c.f;
}

// fp32 -> bf16, 4 elems/thread
__global__ __launch_bounds__(256) void cvt_x_k(const float* __restrict__ in,
                                               unsigned short* __restrict__ out,
                                               int n4) {
    int i = blockIdx.x * 256 + threadIdx.x;
    if (i >= n4) return;
    float4 v = reinterpret_cast<const float4*>(in)[i];
    ushort4 o;
    o.x = f2bf(v.x); o.y = f2bf(v.y); o.z = f2bf(v.z); o.w = f2bf(v.w);
    reinterpret_cast<ushort4*>(out)[i] = o;
}

// Build Wcat[e][m*128+d] = W[m][d][e] (m<8) / root[d][e] (m==8), bf16, both layers.
__global__ __launch_bounds__(256) void cvt_w_k(const float* __restrict__ W1,
                                               const float* __restrict__ r1,
                                               const float* __restrict__ W2,
                                               const float* __restrict__ r2,
                                               unsigned short* __restrict__ wc1,
                                               unsigned short* __restrict__ wc2) {
    int idx = blockIdx.x * 256 + threadIdx.x;       // 0 .. 2*128*1152-1
    int l   = idx / (DD * KCAT);
    int rem = idx % (DD * KCAT);
    int e   = rem / KCAT;
    int md  = rem % KCAT;
    int m = md / DD, d = md % DD;
    const float* W = (l == 0) ? W1 : W2;
    const float* rt = (l == 0) ? r1 : r2;
    float v = (m < 8) ? W[(size_t)m * DD * DD + (size_t)d * DD + e]
                      : rt[(size_t)d * DD + e];
    ((l == 0) ? wc1 : wc2)[rem] = f2bf(v);
}

// total degree per dst
__global__ __launch_bounds__(256) void hist_k(const int* __restrict__ dst,
                                              unsigned int* __restrict__ degTot) {
    int e = blockIdx.x * 256 + threadIdx.x;
    if (e >= NE) return;
    atomicAdd(&degTot[dst[e]], 1u);
}

// unordered segment bases: pos[i] = atomicAdd(counter, degTot[i])
__global__ __launch_bounds__(256) void offsets_k(const unsigned int* __restrict__ degTot,
                                                 unsigned int* __restrict__ counter,
                                                 unsigned int* __restrict__ pos) {
    int i = blockIdx.x * 256 + threadIdx.x;
    if (i >= NN) return;
    pos[i] = atomicAdd(counter, degTot[i]);
}

// scatter src|r<<20 into per-dst segments; afterwards pos[d] == segment end
__global__ __launch_bounds__(256) void fill_k(const int* __restrict__ src,
                                              const int* __restrict__ dst,
                                              const int* __restrict__ et,
                                              unsigned int* __restrict__ pos,
                                              unsigned int* __restrict__ sorted) {
    int e = blockIdx.x * 256 + threadIdx.x;
    if (e >= NE) return;
    unsigned int p = atomicAdd(&pos[dst[e]], 1u);
    sorted[p] = (unsigned int)src[e] | ((unsigned int)et[e] << 20);
}

// Fused RGCN layer. Block = 16 dst nodes, 4 waves (wave owns 4 nodes).
// Phase 1: per node, walk dst segment; per-relation mean of x[src] in VGPRs;
//          write bf16 row xagg[16][1152] (slices r=0..7 + root x at slice 8),
//          XOR-swizzled (slot ^= row&7) for conflict-free b128 reads.
// Phase 2: out[16 nodes][128] = xagg @ Wcat^T via MFMA, +bias, relu.
// mode 1: bf16 store (next layer input); mode 2: f32 store (final output).
__global__ __launch_bounds__(256, 4) void fused_k(const unsigned short* __restrict__ xb,
                                                  const unsigned short* __restrict__ wcat,
                                                  const float* __restrict__ bias,
                                                  const unsigned int* __restrict__ sorted,
                                                  const unsigned int* __restrict__ pos,
                                                  const unsigned int* __restrict__ degTot,
                                                  unsigned short* __restrict__ obf,
                                                  float* __restrict__ of32,
                                                  int mode) {
    __shared__ unsigned short ldsx[16 * KCAT];      // 36,864 B
    const int wave = threadIdx.x >> 6;
    const int lane = threadIdx.x & 63;
    const int c16  = lane & 15;
    const int grp  = lane >> 4;
    const int blk  = blockIdx.x;

    // ---------- phase 1: gather + aggregate ----------
    for (int nl = 0; nl < 4; ++nl) {
        const int row  = wave * 4 + nl;             // LDS row 0..15
        const int node = blk * 16 + row;            // < NN always (6250*16 = NN)
        const unsigned int len = degTot[node];
        const unsigned int end = pos[node];
        const unsigned int beg = end - len;

        float a0x=0.f,a0y=0.f,a1x=0.f,a1y=0.f,a2x=0.f,a2y=0.f,a3x=0.f,a3y=0.f;
        float a4x=0.f,a4y=0.f,a5x=0.f,a5y=0.f,a6x=0.f,a6y=0.f,a7x=0.f,a7y=0.f;
        unsigned long long c0 = 0ull, c1 = 0ull;

        for (unsigned int j0 = beg; j0 < end; j0 += 8) {
            int n = (int)(end - j0); if (n > 8) n = 8;
            unsigned int pk[8], hv[8];
#pragma unroll
            for (int u = 0; u < 8; ++u)
                if (u < n) pk[u] = sorted[j0 + u];
#pragma unroll
            for (int u = 0; u < 8; ++u)
                if (u < n) hv[u] = *reinterpret_cast<const unsigned int*>(
                        xb + (size_t)(pk[u] & 0x1FFFFu) * DD + lane * 2);
#pragma unroll
            for (int u = 0; u < 8; ++u)
                if (u < n) {
                    unsigned int r = pk[u] >> 20;
                    if (r < 4) c0 += 1ull << (16 * r); else c1 += 1ull << (16 * (r - 4));
                    float f0 = bf2f((unsigned short)(hv[u] & 0xffffu));
                    float f1 = bf2f((unsigned short)(hv[u] >> 16));
                    switch (r) {
                        case 0: a0x += f0; a0y += f1; break;
                        case 1: a1x += f0; a1y += f1; break;
                        case 2: a2x += f0; a2y += f1; break;
                        case 3: a3x += f0; a3y += f1; break;
                        case 4: a4x += f0; a4y += f1; break;
                        case 5: a5x += f0; a5y += f1; break;
                        case 6: a6x += f0; a6y += f1; break;
                        default: a7x += f0; a7y += f1; break;
                    }
                }
        }

        // scale by 1/deg_r, cvt, swizzled LDS write (slice r)
        const int sbase = row * (KCAT / 2);         // u32 units: 576 per row
        const int lq = lane >> 2, lm = lane & 3;
        unsigned int* lds32 = reinterpret_cast<unsigned int*>(ldsx);
#pragma unroll
        for (int r = 0; r < 8; ++r) {
            unsigned int cnt = (unsigned int)((((r < 4) ? c0 : c1) >> (16 * (r & 3))) & 0xFFFFu);
            float sc = (cnt > 0) ? __builtin_amdgcn_rcpf((float)cnt) : 0.f;
            float vx, vy;
            switch (r) {
                case 0: vx = a0x; vy = a0y; break;
                case 1: vx = a1x; vy = a1y; break;
                case 2: vx = a2x; vy = a2y; break;
                case 3: vx = a3x; vy = a3y; break;
                case 4: vx = a4x; vy = a4y; break;
                case 5: vx = a5x; vy = a5y; break;
                case 6: vx = a6x; vy = a6y; break;
                default: vx = a7x; vy = a7y; break;
            }
            unsigned int w32 = ((unsigned int)f2bf(vy * sc) << 16) | (unsigned int)f2bf(vx * sc);
            int slot = (r * 16 + lq) ^ (row & 7);   // XOR flips low3 of lq only
            lds32[sbase + slot * 4 + lm] = w32;
        }
        // root slice (m=8): x[node] already bf16
        {
            unsigned int w32 = *reinterpret_cast<const unsigned int*>(
                xb + (size_t)node * DD + lane * 2);
            int slot = (8 * 16 + lq) ^ (row & 7);
            lds32[sbase + slot * 4 + lm] = w32;
        }
    }
    __syncthreads();

    // ---------- phase 2: MFMA out = xagg @ Wcat^T ----------
    const int outb = wave * 32;                     // two 16-wide out tiles
    f32x4 acc0 = f32x4{0.f, 0.f, 0.f, 0.f};
    f32x4 acc1 = f32x4{0.f, 0.f, 0.f, 0.f};
    const unsigned short* arow0 = wcat + (size_t)(outb + c16) * KCAT;
    const unsigned short* arow1 = arow0 + 16 * KCAT;
#pragma unroll
    for (int kk = 0; kk < KCAT / 32; ++kk) {        // 36 k-steps
        int slot = (kk * 4 + grp) ^ (c16 & 7);
        bf16x8 b  = *reinterpret_cast<const bf16x8*>(&ldsx[c16 * KCAT + slot * 8]);
        bf16x8 a0 = *reinterpret_cast<const bf16x8*>(arow0 + kk * 32 + grp * 8);
        bf16x8 a1 = *reinterpret_cast<const bf16x8*>(arow1 + kk * 32 + grp * 8);
        acc0 = __builtin_amdgcn_mfma_f32_16x16x32_bf16(a0, b, acc0, 0, 0, 0);
        acc1 = __builtin_amdgcn_mfma_f32_16x16x32_bf16(a1, b, acc1, 0, 0, 0);
    }

    // ---------- epilogue: +bias, relu, store ----------
    const int node = blk * 16 + c16;
#pragma unroll
    for (int t = 0; t < 2; ++t) {
        const f32x4 acc = t ? acc1 : acc0;
        const int od = outb + t * 16 + grp * 4;
        const float4 bv = *reinterpret_cast<const float4*>(bias + od);
        float o0 = fmaxf(acc[0] + bv.x, 0.f);
        float o1 = fmaxf(acc[1] + bv.y, 0.f);
        float o2 = fmaxf(acc[2] + bv.z, 0.f);
        float o3 = fmaxf(acc[3] + bv.w, 0.f);
        if (mode == 1) {
            union { unsigned short s[4]; uint2 v; } pko;
            pko.s[0] = f2bf(o0); pko.s[1] = f2bf(o1);
            pko.s[2] = f2bf(o2); pko.s[3] = f2bf(o3);
            *reinterpret_cast<uint2*>(obf + (size_t)node * DD + od) = pko.v;
        } else {
            *reinterpret_cast<float4*>(of32 + (size_t)node * DD + od)
                = make_float4(o0, o1, o2, o3);
        }
    }
}

extern "C" void kernel_launch(void* const* d_in, const int* in_sizes, int n_in,
                              void* d_out, int out_size, void* d_ws, size_t ws_size,
                              hipStream_t stream) {
    const float* x  = (const float*)d_in[0];
    const int*   ei = (const int*)d_in[1];
    const int*   et = (const int*)d_in[2];
    const float* W1 = (const float*)d_in[3];
    const float* r1 = (const float*)d_in[4];
    const float* b1 = (const float*)d_in[5];
    const float* W2 = (const float*)d_in[6];
    const float* r2 = (const float*)d_in[7];
    const float* b2 = (const float*)d_in[8];
    float* out = (float*)d_out;

    // workspace (~57 MB)
    char* ws = (char*)d_ws;
    unsigned int*   degTot  = (unsigned int*)ws;                 // NN u32 (pad to 400,256)
    unsigned int*   counter = degTot + NN;
    unsigned int*   pos     = (unsigned int*)(ws + 400256);      // NN u32
    unsigned int*   sorted  = (unsigned int*)(ws + 800256);      // NE u32 = 4 MB
    unsigned short* wc1     = (unsigned short*)(ws + 4800256);   // 128*1152 bf16 = 294,912 B
    unsigned short* wc2     = wc1 + DD * KCAT;
    unsigned short* xbuf    = wc2 + DD * KCAT;                   // 25.6 MB
    unsigned short* xbuf2   = xbuf + (size_t)NN * DD;            // 25.6 MB
    size_t need = (size_t)((char*)(xbuf2 + (size_t)NN * DD) - ws);
    if (ws_size < need) return;                                  // loud failure

    const int* srcv = ei;
    const int* dstv = ei + NE;

    hipMemsetAsync(degTot, 0, 400256, stream);                   // degTot + counter
    cvt_x_k<<<(NN * DD / 4) / 256, 256, 0, stream>>>(x, xbuf, NN * DD / 4);
    cvt_w_k<<<(2 * DD * KCAT) / 256, 256, 0, stream>>>(W1, r1, W2, r2, wc1, wc2);
    hist_k<<<(NE + 255) / 256, 256, 0, stream>>>(dstv, degTot);
    offsets_k<<<(NN + 255) / 256, 256, 0, stream>>>(degTot, counter, pos);
    fill_k<<<(NE + 255) / 256, 256, 0, stream>>>(srcv, dstv, et, pos, sorted);

    fused_k<<<NBLK, 256, 0, stream>>>(xbuf,  wc1, b1, sorted, pos, degTot,
                                      xbuf2, (float*)nullptr, 1);
    fused_k<<<NBLK, 256, 0, stream>>>(xbuf2, wc2, b2, sorted, pos, degTot,
                                      (unsigned short*)nullptr, out, 2);
}

// Round 6
// 586.447 us; speedup vs baseline: 3.4936x; 1.3801x over previous
//
#include <hip/hip_runtime.h>
#include <hip/hip_bf16.h>

#define NN 100000
#define NE 1000000
#define DD 128
#define RR 8
#define KCAT 1152              // 9*128 (8 relations + root)
#define NBLK 6250              // NN/16 exactly

typedef short bf16x8 __attribute__((ext_vector_type(8)));
typedef float f32x4 __attribute__((ext_vector_type(4)));

__device__ __forceinline__ unsigned short f2bf(float f) {
    union { float f; unsigned int u; } c; c.f = f;
    unsigned int u = c.u;
    u += 0x7fffu + ((u >> 16) & 1u);   // round-to-nearest-even
    return (unsigned short)(u >> 16);
}

// fp32 -> bf16, 4 elems/thread
__global__ __launch_bounds__(256) void cvt_x_k(const float* __restrict__ in,
                                               unsigned short* __restrict__ out,
                                               int n4) {
    int i = blockIdx.x * 256 + threadIdx.x;
    if (i >= n4) return;
    float4 v = reinterpret_cast<const float4*>(in)[i];
    ushort4 o;
    o.x = f2bf(v.x); o.y = f2bf(v.y); o.z = f2bf(v.z); o.w = f2bf(v.w);
    reinterpret_cast<ushort4*>(out)[i] = o;
}

// Build Wcat[e][m*128+d] = W[m][d][e] (m<8) / root[d][e] (m==8), bf16, both layers.
__global__ __launch_bounds__(256) void cvt_w_k(const float* __restrict__ W1,
                                               const float* __restrict__ r1,
                                               const float* __restrict__ W2,
                                               const float* __restrict__ r2,
                                               unsigned short* __restrict__ wc1,
                                               unsigned short* __restrict__ wc2) {
    int idx = blockIdx.x * 256 + threadIdx.x;       // 0 .. 2*128*1152-1
    int l   = idx / (DD * KCAT);
    int rem = idx % (DD * KCAT);
    int e   = rem / KCAT;
    int md  = rem % KCAT;
    int m = md / DD, d = md % DD;
    const float* W = (l == 0) ? W1 : W2;
    const float* rt = (l == 0) ? r1 : r2;
    float v = (m < 8) ? W[(size_t)m * DD * DD + (size_t)d * DD + e]
                      : rt[(size_t)d * DD + e];
    ((l == 0) ? wc1 : wc2)[rem] = f2bf(v);
}

// per-(dst, r) degree
__global__ __launch_bounds__(256) void hist8_k(const int* __restrict__ dst,
                                               const int* __restrict__ et,
                                               unsigned int* __restrict__ deg8) {
    int e = blockIdx.x * 256 + threadIdx.x;
    if (e >= NE) return;
    atomicAdd(&deg8[(size_t)dst[e] * 8 + et[e]], 1u);
}

// Per node: padded segment base (unordered alloc), per-r sub-bases, dummy pads.
__global__ __launch_bounds__(256) void offs8_k(const unsigned int* __restrict__ deg8,
                                               unsigned int* __restrict__ counter,
                                               unsigned int* __restrict__ pos8,
                                               unsigned int* __restrict__ segBeg,
                                               unsigned int* __restrict__ segLen,
                                               unsigned int* __restrict__ sorted) {
    int node = blockIdx.x * 256 + threadIdx.x;
    if (node >= NN) return;
    const uint4* dp = reinterpret_cast<const uint4*>(&deg8[(size_t)node * 8]);
    uint4 a = dp[0], b = dp[1];
    unsigned int tot = a.x + a.y + a.z + a.w + b.x + b.y + b.z + b.w;
    unsigned int padTot = (tot + 7u) & ~7u;
    unsigned int base = atomicAdd(counter, padTot);
    unsigned int* pp = &pos8[(size_t)node * 8];
    unsigned int run = base;
    pp[0] = run; run += a.x;  pp[1] = run; run += a.y;
    pp[2] = run; run += a.z;  pp[3] = run; run += a.w;
    pp[4] = run; run += b.x;  pp[5] = run; run += b.y;
    pp[6] = run; run += b.z;  pp[7] = run; run += b.w;
    segBeg[node] = base;
    segLen[node] = padTot;
    for (unsigned int p = base + tot; p < base + padTot; ++p)
        sorted[p] = 0xF00000u;                      // dummy: src=0, r=15, deg=0
}

// scatter src | r<<20 | deg<<24 into per-(dst,r) slots (bumps pos8)
__global__ __launch_bounds__(256) void fill8_k(const int* __restrict__ src,
                                               const int* __restrict__ dst,
                                               const int* __restrict__ et,
                                               const unsigned int* __restrict__ deg8,
                                               unsigned int* __restrict__ pos8,
                                               unsigned int* __restrict__ sorted) {
    int e = blockIdx.x * 256 + threadIdx.x;
    if (e >= NE) return;
    int d = dst[e], r = et[e];
    unsigned int p = atomicAdd(&pos8[(size_t)d * 8 + r], 1u);
    unsigned int dg = deg8[(size_t)d * 8 + r];
    if (dg > 255u) dg = 255u;
    sorted[p] = (unsigned int)src[e] | ((unsigned int)r << 20) | (dg << 24);
}

// Fused RGCN layer. Block = 16 dst nodes, 4 waves (wave owns 4 nodes).
// Phase 1: per node, walk r-sorted padded segment; run-accumulate x[src];
//          flush each relation run (scaled by 1/deg) into swizzled LDS slice;
//          root x at slice 8.
// Phase 2: out[16][128] = xagg @ Wcat^T via MFMA, +bias, relu.
// mode 1: bf16 store (next layer input); mode 2: f32 store (final output).
__global__ __launch_bounds__(256, 4) void fused_k(const unsigned short* __restrict__ xb,
                                                  const unsigned short* __restrict__ wcat,
                                                  const float* __restrict__ bias,
                                                  const unsigned int* __restrict__ sorted,
                                                  const unsigned int* __restrict__ segBeg,
                                                  const unsigned int* __restrict__ segLen,
                                                  unsigned short* __restrict__ obf,
                                                  float* __restrict__ of32,
                                                  int mode) {
    __shared__ unsigned short ldsx[16 * KCAT];      // 36,864 B
    const int wave = threadIdx.x >> 6;
    const int lane = threadIdx.x & 63;
    const int c16  = lane & 15;
    const int grp  = lane >> 4;
    const int lq   = lane >> 2;
    const int lm   = lane & 3;
    const int blk  = blockIdx.x;
    unsigned int* lds32 = reinterpret_cast<unsigned int*>(ldsx);

    // ---------- phase 1: gather + run-flush aggregate ----------
    for (int nl = 0; nl < 4; ++nl) {
        const int row  = wave * 4 + nl;             // LDS row 0..15
        const int node = blk * 16 + row;            // < NN (6250*16 == NN)
        const int sbase = row * (KCAT / 2);         // u32 units per row: 576
        const int xorv = row & 7;

        // pre-zero the 8 relation slices; write root slice (m=8)
#pragma unroll
        for (int r = 0; r < 8; ++r) {
            int slot = (r * 16 + lq) ^ xorv;
            lds32[sbase + slot * 4 + lm] = 0u;
        }
        {
            unsigned int w32 = *reinterpret_cast<const unsigned int*>(
                xb + (size_t)node * DD + lane * 2);
            int slot = (8 * 16 + lq) ^ xorv;
            lds32[sbase + slot * 4 + lm] = w32;
        }

        const unsigned int beg  = segBeg[node];
        const unsigned int lenP = segLen[node];     // multiple of 8
        const unsigned int* segp = sorted + (unsigned int)__builtin_amdgcn_readfirstlane((int)beg);

        float ax = 0.f, ay = 0.f, scRun = 0.f;
        unsigned int rcur = 15u;

        for (unsigned int j = 0; j < lenP; j += 8) {
            unsigned int pk[8], hv[8];
#pragma unroll
            for (int u = 0; u < 8; ++u) pk[u] = segp[j + u];
#pragma unroll
            for (int u = 0; u < 8; ++u)
                hv[u] = *reinterpret_cast<const unsigned int*>(
                    xb + (size_t)(pk[u] & 0x1FFFFu) * DD + lane * 2);
#pragma unroll
            for (int u = 0; u < 8; ++u) {
                unsigned int r = (pk[u] >> 20) & 0xFu;
                if (r != rcur) {
                    if (rcur < 8u) {
                        unsigned int w32 = ((unsigned int)f2bf(ay * scRun) << 16)
                                         | (unsigned int)f2bf(ax * scRun);
                        int slot = ((int)rcur * 16 + lq) ^ xorv;
                        lds32[sbase + slot * 4 + lm] = w32;
                    }
                    rcur  = r;
                    scRun = __builtin_amdgcn_rcpf((float)(pk[u] >> 24));
                    ax = 0.f; ay = 0.f;
                }
                union { unsigned int u32; float f; } c0, c1;
                c0.u32 = hv[u] << 16;
                c1.u32 = hv[u] & 0xffff0000u;
                ax += c0.f; ay += c1.f;
            }
        }
        if (rcur < 8u) {
            unsigned int w32 = ((unsigned int)f2bf(ay * scRun) << 16)
                             | (unsigned int)f2bf(ax * scRun);
            int slot = ((int)rcur * 16 + lq) ^ xorv;
            lds32[sbase + slot * 4 + lm] = w32;
        }
    }
    __syncthreads();

    // ---------- phase 2: MFMA out = xagg @ Wcat^T ----------
    const int outb = wave * 32;                     // two 16-wide out tiles
    f32x4 acc0 = f32x4{0.f, 0.f, 0.f, 0.f};
    f32x4 acc1 = f32x4{0.f, 0.f, 0.f, 0.f};
    const unsigned short* arow0 = wcat + (size_t)(outb + c16) * KCAT;
    const unsigned short* arow1 = arow0 + 16 * KCAT;
#pragma unroll
    for (int kk = 0; kk < KCAT / 32; ++kk) {        // 36 k-steps
        int slot = (kk * 4 + grp) ^ (c16 & 7);
        bf16x8 b  = *reinterpret_cast<const bf16x8*>(&ldsx[c16 * KCAT + slot * 8]);
        bf16x8 a0 = *reinterpret_cast<const bf16x8*>(arow0 + kk * 32 + grp * 8);
        bf16x8 a1 = *reinterpret_cast<const bf16x8*>(arow1 + kk * 32 + grp * 8);
        acc0 = __builtin_amdgcn_mfma_f32_16x16x32_bf16(a0, b, acc0, 0, 0, 0);
        acc1 = __builtin_amdgcn_mfma_f32_16x16x32_bf16(a1, b, acc1, 0, 0, 0);
    }

    // ---------- epilogue: +bias, relu, store ----------
    const int node = blk * 16 + c16;
#pragma unroll
    for (int t = 0; t < 2; ++t) {
        const f32x4 acc = t ? acc1 : acc0;
        const int od = outb + t * 16 + grp * 4;
        const float4 bv = *reinterpret_cast<const float4*>(bias + od);
        float o0 = fmaxf(acc[0] + bv.x, 0.f);
        float o1 = fmaxf(acc[1] + bv.y, 0.f);
        float o2 = fmaxf(acc[2] + bv.z, 0.f);
        float o3 = fmaxf(acc[3] + bv.w, 0.f);
        if (mode == 1) {
            union { unsigned short s[4]; uint2 v; } pko;
            pko.s[0] = f2bf(o0); pko.s[1] = f2bf(o1);
            pko.s[2] = f2bf(o2); pko.s[3] = f2bf(o3);
            *reinterpret_cast<uint2*>(obf + (size_t)node * DD + od) = pko.v;
        } else {
            *reinterpret_cast<float4*>(of32 + (size_t)node * DD + od)
                = make_float4(o0, o1, o2, o3);
        }
    }
}

extern "C" void kernel_launch(void* const* d_in, const int* in_sizes, int n_in,
                              void* d_out, int out_size, void* d_ws, size_t ws_size,
                              hipStream_t stream) {
    const float* x  = (const float*)d_in[0];
    const int*   ei = (const int*)d_in[1];
    const int*   et = (const int*)d_in[2];
    const float* W1 = (const float*)d_in[3];
    const float* r1 = (const float*)d_in[4];
    const float* b1 = (const float*)d_in[5];
    const float* W2 = (const float*)d_in[6];
    const float* r2 = (const float*)d_in[7];
    const float* b2 = (const float*)d_in[8];
    float* out = (float*)d_out;

    // workspace (~66 MB)
    char* ws = (char*)d_ws;
    unsigned int*   deg8    = (unsigned int*)ws;                 // NN*8 u32 = 3.2 MB
    unsigned int*   counter = deg8 + (size_t)NN * 8;             // 1 u32 (pad 64)
    unsigned int*   pos8    = counter + 64;                      // NN*8 u32 = 3.2 MB
    unsigned int*   segBeg  = pos8 + (size_t)NN * 8;             // NN u32
    unsigned int*   segLen  = segBeg + NN;                       // NN u32
    unsigned int*   sorted  = segLen + NN;                       // (NE+7*NN) u32 = 6.8 MB
    unsigned short* wc1     = (unsigned short*)(sorted + NE + 7 * NN);  // 294,912 B
    unsigned short* wc2     = wc1 + DD * KCAT;
    unsigned short* xbuf    = wc2 + DD * KCAT;                   // 25.6 MB
    unsigned short* xbuf2   = xbuf + (size_t)NN * DD;            // 25.6 MB
    size_t need = (size_t)((char*)(xbuf2 + (size_t)NN * DD) - ws);
    if (ws_size < need) return;                                  // loud failure

    const int* srcv = ei;
    const int* dstv = ei + NE;

    hipMemsetAsync(deg8, 0, ((size_t)NN * 8 + 64) * 4, stream);  // deg8 + counter
    cvt_x_k<<<(NN * DD / 4) / 256, 256, 0, stream>>>(x, xbuf, NN * DD / 4);
    cvt_w_k<<<(2 * DD * KCAT) / 256, 256, 0, stream>>>(W1, r1, W2, r2, wc1, wc2);
    hist8_k<<<(NE + 255) / 256, 256, 0, stream>>>(dstv, et, deg8);
    offs8_k<<<(NN + 255) / 256, 256, 0, stream>>>(deg8, counter, pos8, segBeg, segLen, sorted);
    fill8_k<<<(NE + 255) / 256, 256, 0, stream>>>(srcv, dstv, et, deg8, pos8, sorted);

    fused_k<<<NBLK, 256, 0, stream>>>(xbuf,  wc1, b1, sorted, segBeg, segLen,
                                      xbuf2, (float*)nullptr, 1);
    fused_k<<<NBLK, 256, 0, stream>>>(xbuf2, wc2, b2, sorted, segBeg, segLen,
                                      (unsigned short*)nullptr, out, 2);
}